// Round 8
// baseline (1506.570 us; speedup 1.0000x reference)
//
#include <hip/hip_runtime.h>
#include <stdint.h>

#define HID    2048
#define MPTS   16425
#define MTILES 129    // ceil(16425/128)
#define NTIL   16     // 2048/128
#define KTIL   64     // 2048/32
#define BIMG   5120   // shorts per packed B tile image (128 rows * 40)

typedef float f32x4  __attribute__((ext_vector_type(4)));
typedef short bf16x8 __attribute__((ext_vector_type(8)));

__device__ __forceinline__ float bf2f(unsigned short h) {
    unsigned u = ((unsigned)h) << 16;
    return __builtin_bit_cast(float, u);
}
__device__ __forceinline__ unsigned short f2bf(float f) {
    unsigned u = __builtin_bit_cast(unsigned, f);
    u = u + 0x7FFFu + ((u >> 16) & 1u);
    return (unsigned short)(u >> 16);
}

// ---------------------------------------------------------------------------
// Pack fp32 W (K x N row-major) into hi/lo bf16 padded tile images:
// img(L,nt,kt)[n*40+k] = W[kt*32+k][nt*128+n]; W ~= hi + lo (bf16 pair)
// ---------------------------------------------------------------------------
__global__ void pack_w_hl(const float* __restrict__ w1,
                          const float* __restrict__ w2,
                          const float* __restrict__ w3,
                          unsigned short* __restrict__ wph,
                          unsigned short* __restrict__ wpl) {
    const int kt = blockIdx.x, nt = blockIdx.y, L = blockIdx.z;
    const float* W = (L == 0) ? w1 : ((L == 1) ? w2 : w3);
    __shared__ float tl[128 * 33];   // [n][k] transposed, padded
    const int tid = threadIdx.x;
    const int k  = tid >> 3;          // 0..31
    const int nc = (tid & 7) * 16;    // 0..112
    const float* src = W + (size_t)(kt * 32 + k) * HID + nt * 128 + nc;
    #pragma unroll
    for (int j = 0; j < 16; ++j) tl[(nc + j) * 33 + k] = src[j];
    __syncthreads();
    const size_t base = (size_t)(L * 1024 + nt * 64 + kt) * BIMG;
    for (int e = tid; e < BIMG; e += 256) {
        int n = e / 40, kk = e - n * 40;
        float a = (kk < 32) ? tl[n * 33 + kk] : 0.f;
        unsigned short hs = f2bf(a);
        wph[base + e] = hs;
        wpl[base + e] = f2bf(a - bf2f(hs));
    }
}

// ---------------------------------------------------------------------------
// Layer 0: A[r][j] = relu(xs[row0+r]*w0[j] + b0[j]), fp32
// ---------------------------------------------------------------------------
__global__ void layer0(const float* __restrict__ xs,
                       const float* __restrict__ w0,
                       const float* __restrict__ b0,
                       float* __restrict__ A, int row0) {
    const int r = blockIdx.x;
    const int grow = row0 + r;
    const int j = threadIdx.x * 8;
    const float x = (grow < MPTS) ? xs[grow] : 0.f;
    float* out = A + (size_t)r * HID + j;
    #pragma unroll
    for (int q = 0; q < 8; ++q) {
        float v = x * w0[j + q] + b0[j + q];
        out[q] = v > 0.f ? v : 0.f;
    }
}

// ---------------------------------------------------------------------------
// MFMA GEMM: C = relu(A @ W + b), ~fp32 accuracy via hi/lo bf16 splits.
// A fp32 (split per k-step), W pre-split images. 128x128 tile, BK=32,
// 4 waves of 64x64, 3x mfma_f32_16x16x32_bf16 per fragment pair
// (AhBh + AlBh + AhBl; AlBl term ~2^-17 relative, dropped).
// ---------------------------------------------------------------------------
__launch_bounds__(256, 2)
__global__ void gemm_mfma(const float* __restrict__ A,
                          const unsigned short* __restrict__ wph,
                          const unsigned short* __restrict__ wpl,
                          const float* __restrict__ bias,
                          float* __restrict__ C, int layer) {
    __shared__ short Ah[128 * 40];
    __shared__ short Al[128 * 40];
    __shared__ short Bh[128 * 40];
    __shared__ short Bl[128 * 40];

    const int tid  = threadIdx.x;
    const int lane = tid & 63;
    const int wave = tid >> 6;
    const int quad = lane >> 4;
    const int lidx = lane & 15;
    const int nt = blockIdx.x;
    const int m0 = blockIdx.y * 128;    // chunk-local
    const int mbase = (wave >> 1) * 64;
    const int nbase = (wave & 1) * 64;

    const size_t wbase = (size_t)(layer * 1024 + nt * 64) * BIMG;
    const bf16x8* gH = (const bf16x8*)(wph + wbase);
    const bf16x8* gL = (const bf16x8*)(wpl + wbase);

    // A staging: 512 chunks of 8 fp32 (128 rows x 4 kchunks); 2 per thread
    const int mr0 = tid >> 2,         kc0 = tid & 3;
    const int mr1 = (tid + 256) >> 2, kc1 = (tid + 256) & 3;
    const float* a0p = A + (size_t)(m0 + mr0) * HID + kc0 * 8;
    const float* a1p = A + (size_t)(m0 + mr1) * HID + kc1 * 8;

    f32x4 acc[4][4];
    #pragma unroll
    for (int i = 0; i < 4; ++i)
        #pragma unroll
        for (int j = 0; j < 4; ++j) acc[i][j] = (f32x4)0.f;

    for (int kt = 0; kt < KTIL; ++kt) {
        // ---- global prefetch into VGPRs ----
        const float* p0 = a0p + kt * 32;
        const float* p1 = a1p + kt * 32;
        f32x4 av0 = *(const f32x4*)(p0);
        f32x4 av1 = *(const f32x4*)(p0 + 4);
        f32x4 av2 = *(const f32x4*)(p1);
        f32x4 av3 = *(const f32x4*)(p1 + 4);

        const int kb = kt * 640;   // vec8 chunks per k-step image
        bf16x8 bh0 = gH[kb + tid];
        bf16x8 bh1 = gH[kb + tid + 256];
        bf16x8 bl0 = gL[kb + tid];
        bf16x8 bl1 = gL[kb + tid + 256];
        bf16x8 bh2, bl2;
        if (tid < 128) { bh2 = gH[kb + tid + 512]; bl2 = gL[kb + tid + 512]; }

        __syncthreads();   // prior iteration's fragment reads done

        // ---- B: VGPR -> LDS ----
        ((bf16x8*)Bh)[tid]       = bh0;  ((bf16x8*)Bl)[tid]       = bl0;
        ((bf16x8*)Bh)[tid + 256] = bh1;  ((bf16x8*)Bl)[tid + 256] = bl1;
        if (tid < 128) { ((bf16x8*)Bh)[tid + 512] = bh2; ((bf16x8*)Bl)[tid + 512] = bl2; }

        // ---- A: fp32 -> bf16 hi + lo ----
        {
            bf16x8 h, l;
            #pragma unroll
            for (int q = 0; q < 4; ++q) { float a = av0[q]; unsigned short hs = f2bf(a); h[q] = (short)hs; l[q] = (short)f2bf(a - bf2f(hs)); }
            #pragma unroll
            for (int q = 0; q < 4; ++q) { float a = av1[q]; unsigned short hs = f2bf(a); h[4+q] = (short)hs; l[4+q] = (short)f2bf(a - bf2f(hs)); }
            *(bf16x8*)(&Ah[mr0 * 40 + kc0 * 8]) = h;
            *(bf16x8*)(&Al[mr0 * 40 + kc0 * 8]) = l;
            #pragma unroll
            for (int q = 0; q < 4; ++q) { float a = av2[q]; unsigned short hs = f2bf(a); h[q] = (short)hs; l[q] = (short)f2bf(a - bf2f(hs)); }
            #pragma unroll
            for (int q = 0; q < 4; ++q) { float a = av3[q]; unsigned short hs = f2bf(a); h[4+q] = (short)hs; l[4+q] = (short)f2bf(a - bf2f(hs)); }
            *(bf16x8*)(&Ah[mr1 * 40 + kc1 * 8]) = h;
            *(bf16x8*)(&Al[mr1 * 40 + kc1 * 8]) = l;
        }
        __syncthreads();   // staging visible

        bf16x8 afh[4], afl[4], bfh[4], bfl[4];
        #pragma unroll
        for (int mm = 0; mm < 4; ++mm) {
            int r = mbase + mm * 16 + lidx;
            afh[mm] = *(const bf16x8*)(&Ah[r * 40 + quad * 8]);
            afl[mm] = *(const bf16x8*)(&Al[r * 40 + quad * 8]);
        }
        #pragma unroll
        for (int nn = 0; nn < 4; ++nn) {
            int r = nbase + nn * 16 + lidx;
            bfh[nn] = *(const bf16x8*)(&Bh[r * 40 + quad * 8]);
            bfl[nn] = *(const bf16x8*)(&Bl[r * 40 + quad * 8]);
        }
        #pragma unroll
        for (int mm = 0; mm < 4; ++mm)
            #pragma unroll
            for (int nn = 0; nn < 4; ++nn) {
                acc[mm][nn] = __builtin_amdgcn_mfma_f32_16x16x32_bf16(afh[mm], bfh[nn], acc[mm][nn], 0, 0, 0);
                acc[mm][nn] = __builtin_amdgcn_mfma_f32_16x16x32_bf16(afl[mm], bfh[nn], acc[mm][nn], 0, 0, 0);
                acc[mm][nn] = __builtin_amdgcn_mfma_f32_16x16x32_bf16(afh[mm], bfl[nn], acc[mm][nn], 0, 0, 0);
            }
    }

    // epilogue: C/D layout col=lane&15, row=quad*4+reg (m89-verified)
    #pragma unroll
    for (int nn = 0; nn < 4; ++nn) {
        const int col = nt * 128 + nbase + nn * 16 + lidx;
        const float bv = bias[col];
        #pragma unroll
        for (int mm = 0; mm < 4; ++mm) {
            const int mrow = m0 + mbase + mm * 16 + quad * 4;
            #pragma unroll
            for (int r = 0; r < 4; ++r) {
                float v = acc[mm][nn][r] + bv;
                C[(size_t)(mrow + r) * HID + col] = v > 0.f ? v : 0.f;
            }
        }
    }
}

// ---------------------------------------------------------------------------
// Fallback plain VALU fp32 GEMM (used when ws too small for packed images)
// ---------------------------------------------------------------------------
__launch_bounds__(256)
__global__ void gemm_valu(const float* __restrict__ A,
                          const float* __restrict__ W,
                          const float* __restrict__ bias,
                          float* __restrict__ C) {
    __shared__ float As[16][132];
    __shared__ float Ws[16][132];

    const int tid = threadIdx.x;
    const int tx = tid & 15, ty = tid >> 4;
    const int n0 = blockIdx.x * 128;
    const int m0 = blockIdx.y * 128;

    const int am = tid & 127;
    const int ak = (tid >> 7) * 8;
    const int wn = (tid & 15) * 8;
    const int wk = tid >> 4;

    const float* aptr = A + (size_t)(m0 + am) * HID + ak;
    const float* wptr = W + (size_t)wk * HID + n0 + wn;

    float acc[8][8];
    #pragma unroll
    for (int i = 0; i < 8; ++i)
        #pragma unroll
        for (int j = 0; j < 8; ++j) acc[i][j] = 0.f;

    for (int k0 = 0; k0 < HID; k0 += 16) {
        f32x4 a0 = *(const f32x4*)(aptr + k0);
        f32x4 a1 = *(const f32x4*)(aptr + k0 + 4);
        f32x4 w0v = *(const f32x4*)(wptr + (size_t)k0 * HID);
        f32x4 w1v = *(const f32x4*)(wptr + (size_t)k0 * HID + 4);

        __syncthreads();

        As[ak + 0][am] = a0[0]; As[ak + 1][am] = a0[1];
        As[ak + 2][am] = a0[2]; As[ak + 3][am] = a0[3];
        As[ak + 4][am] = a1[0]; As[ak + 5][am] = a1[1];
        As[ak + 6][am] = a1[2]; As[ak + 7][am] = a1[3];
        *(f32x4*)&Ws[wk][wn]     = w0v;
        *(f32x4*)&Ws[wk][wn + 4] = w1v;

        __syncthreads();

        #pragma unroll
        for (int kk = 0; kk < 16; ++kk) {
            f32x4 av0 = *(const f32x4*)&As[kk][ty * 8];
            f32x4 av1 = *(const f32x4*)&As[kk][ty * 8 + 4];
            f32x4 bv0 = *(const f32x4*)&Ws[kk][tx * 8];
            f32x4 bv1 = *(const f32x4*)&Ws[kk][tx * 8 + 4];
            float a[8] = {av0[0], av0[1], av0[2], av0[3], av1[0], av1[1], av1[2], av1[3]};
            float b[8] = {bv0[0], bv0[1], bv0[2], bv0[3], bv1[0], bv1[1], bv1[2], bv1[3]};
            #pragma unroll
            for (int i = 0; i < 8; ++i)
                #pragma unroll
                for (int j = 0; j < 8; ++j) acc[i][j] += a[i] * b[j];
        }
    }

    #pragma unroll
    for (int i = 0; i < 8; ++i) {
        const int m = m0 + ty * 8 + i;
        #pragma unroll
        for (int jc = 0; jc < 2; ++jc) {
            const int n = n0 + tx * 8 + jc * 4;
            f32x4 v4;
            #pragma unroll
            for (int q = 0; q < 4; ++q) {
                float v = acc[i][jc * 4 + q] + bias[n + q];
                v4[q] = v > 0.f ? v : 0.f;
            }
            *(f32x4*)(C + (size_t)m * HID + n) = v4;
        }
    }
}

// ---------------------------------------------------------------------------
// Layer 4: Amg[row0+r] = relu(dot(A[r,:], w4) + b4); one wave per row
// ---------------------------------------------------------------------------
__global__ void layer4(const float* __restrict__ A,
                       const float* __restrict__ w4,
                       const float* __restrict__ b4,
                       float* __restrict__ Amg, int row0) {
    const int lane = threadIdx.x & 63;
    const int wave = threadIdx.x >> 6;
    const int r    = blockIdx.x * 4 + wave;
    if (row0 + r >= MPTS) return;
    const float* ap = A + (size_t)r * HID;
    float s = 0.f;
    #pragma unroll
    for (int c = 0; c < 8; ++c) {
        const int col = c * 256 + lane * 4;
        f32x4 av = *(const f32x4*)(ap + col);
        f32x4 wv = *(const f32x4*)(w4 + col);
        s += av[0] * wv[0] + av[1] * wv[1] + av[2] * wv[2] + av[3] * wv[3];
    }
    #pragma unroll
    for (int off = 32; off; off >>= 1) s += __shfl_down(s, off);
    if (lane == 0) {
        float v = s + b4[0];
        Amg[row0 + r] = v > 0.f ? v : 0.f;
    }
}

// ---------------------------------------------------------------------------
// Multigrid level: interp (2n-1) + band overwrite. ALL levels write fp32;
// the last level's outf is d_out (reference output dtype = float32).
// nbrs int32 or int64-as-word-pairs (autodetected via zero high words).
// ---------------------------------------------------------------------------
__global__ void mg_level(const float* __restrict__ in, float* __restrict__ outf,
                         const int* __restrict__ nbrs_base, int level,
                         const float* __restrict__ band, int n_out) {
    const int j = blockIdx.x * 256 + threadIdx.x;
    if (j >= n_out) return;
    float v;
    if (j & 1) v = 0.5f * (in[j >> 1] + in[(j >> 1) + 1]);
    else       v = in[j >> 1];
    const int stride =
        (nbrs_base[1] == 0 && nbrs_base[3] == 0 && nbrs_base[5] == 0) ? 2 : 1;
    #pragma unroll
    for (int t = 0; t < 8; ++t) {
        const int idx = nbrs_base[(level * 8 + t) * stride];
        if (j == idx) v = band[t];
    }
    outf[j] = v;
}

// ---------------------------------------------------------------------------
extern "C" void kernel_launch(void* const* d_in, const int* in_sizes, int n_in,
                              void* d_out, int out_size, void* d_ws, size_t ws_size,
                              hipStream_t stream) {
    // ---- input order detection: dict (documented) / signature / alphabetical
    int iXS=0, iNB=1, iW0=4, iB0=5, iW1=6, iB1=7, iW2=8, iB2=9,
        iW3=10, iB3=11, iW4=12, iB4=13;                       // dict default
    if (n_in >= 14) {
        if (in_sizes[0] == HID) {
            // alphabetical: b0,b1,b2,b3,b4,k,m,nbrs,w0,w1,w2,w3,w4,xs
            iB0=0; iB1=1; iB2=2; iB3=3; iB4=4; iNB=7;
            iW0=8; iW1=9; iW2=10; iW3=11; iW4=12; iXS=13;
        } else if (!(in_sizes[1] == 40 || in_sizes[1] == 80)) {
            // signature: xs,w0,b0,w1,b1,w2,b2,w3,b3,w4,b4,nbrs,k,m
            iXS=0; iW0=1; iB0=2; iW1=3; iB1=4; iW2=5; iB2=6;
            iW3=7; iB3=8; iW4=9; iB4=10; iNB=11;
        }
    }
    const float* xs = (const float*)d_in[iXS];
    const int* nbrs = (const int*)d_in[iNB];
    const float* w0 = (const float*)d_in[iW0];
    const float* b0 = (const float*)d_in[iB0];
    const float* w1 = (const float*)d_in[iW1];
    const float* b1 = (const float*)d_in[iB1];
    const float* w2 = (const float*)d_in[iW2];
    const float* b2 = (const float*)d_in[iB2];
    const float* w3 = (const float*)d_in[iW3];
    const float* b3 = (const float*)d_in[iB3];
    const float* w4 = (const float*)d_in[iW4];
    const float* b4 = (const float*)d_in[iB4];

    // ---- workspace layout ----
    char* ws = (char*)d_ws;
    const size_t szAmg = 66048;     // 16512 floats
    const size_t szAh1 = 524544;    // >=131073 floats (levels 0,2)
    const size_t szAh2 = 1048832;   // >=262145 floats (levels 1,3)
    float* Amg = (float*)(ws);
    float* ahA = (float*)(ws + szAmg);
    float* ahB = (float*)(ws + szAmg + szAh1);
    const size_t casc_end = szAmg + szAh1 + szAh2;       // 1,639,424
    const size_t szWHL  = 2ull * 3 * 1024 * BIMG * 2;    // 62,914,560 (hi+lo)
    const size_t per_tile = 2ull * 128 * HID * 4;        // 2 MB (A+B ping-pong)

    const int use_mfma = (ws_size >= casc_end + szWHL + per_tile) ? 1 : 0;

    unsigned short* wph = (unsigned short*)(ws + casc_end);
    unsigned short* wpl = wph + (size_t)3 * 1024 * BIMG;
    const size_t buf_start = use_mfma ? (casc_end + szWHL) : casc_end;

    size_t avail = ws_size - buf_start;
    int CT = (int)(avail / per_tile);
    if (CT < 1) CT = 1;
    if (CT > MTILES) CT = MTILES;

    float* bufA = (float*)(ws + buf_start);
    float* bufB = (float*)(ws + buf_start + (size_t)CT * 128 * HID * 4);

    if (use_mfma)
        pack_w_hl<<<dim3(KTIL, NTIL, 3), 256, 0, stream>>>(w1, w2, w3, wph, wpl);

    for (int t0 = 0; t0 < MTILES; t0 += CT) {
        int tiles = (MTILES - t0 < CT) ? (MTILES - t0) : CT;
        int row0 = t0 * 128;
        layer0<<<dim3(tiles * 128), 256, 0, stream>>>(xs, w0, b0, bufA, row0);
        dim3 ggrid(NTIL, tiles);
        if (use_mfma) {
            gemm_mfma<<<ggrid, 256, 0, stream>>>(bufA, wph, wpl, b1, bufB, 0);
            gemm_mfma<<<ggrid, 256, 0, stream>>>(bufB, wph, wpl, b2, bufA, 1);
            gemm_mfma<<<ggrid, 256, 0, stream>>>(bufA, wph, wpl, b3, bufB, 2);
        } else {
            gemm_valu<<<ggrid, 256, 0, stream>>>(bufA, w1, b1, bufB);
            gemm_valu<<<ggrid, 256, 0, stream>>>(bufB, w2, b2, bufA);
            gemm_valu<<<ggrid, 256, 0, stream>>>(bufA, w3, b3, bufB);
        }
        layer4<<<dim3(tiles * 32), 256, 0, stream>>>(bufB, w4, b4, Amg, row0);
    }

    // multigrid cascade: 16385 -> 32769 -> 65537 -> 131073 -> 262145 -> 524289
    // levels 0..3 -> fp32 ws buffers; level 4 -> d_out as FLOAT32
    const float* cur = Amg + 40;
    float* dsts[5] = {ahA, ahB, ahA, ahB, (float*)d_out};
    int n = 16385;
    for (int i = 0; i < 5; ++i) {
        int n_out = 2 * n - 1;
        mg_level<<<dim3((n_out + 255) / 256), 256, 0, stream>>>(
            cur, dsts[i], nbrs, i, Amg + 8 * (4 - i), n_out);
        cur = dsts[i];
        n = n_out;
    }
    (void)out_size;
}

// Round 9
// 1378.903 us; speedup vs baseline: 1.0926x; 1.0926x over previous
//
#include <hip/hip_runtime.h>
#include <stdint.h>

#define HID    2048
#define MPTS   16425
#define MTILES 129    // ceil(16425/128)
#define NTIL   16     // 2048/128
#define KTIL   64     // 2048/32
#define BIMG   5120   // shorts per packed B tile image (128 rows * 40)

typedef float f32x4  __attribute__((ext_vector_type(4)));
typedef short bf16x8 __attribute__((ext_vector_type(8)));
typedef short bf16x4 __attribute__((ext_vector_type(4)));

__device__ __forceinline__ float bf2f(unsigned short h) {
    unsigned u = ((unsigned)h) << 16;
    return __builtin_bit_cast(float, u);
}
__device__ __forceinline__ unsigned short f2bf(float f) {
    unsigned u = __builtin_bit_cast(unsigned, f);
    u = u + 0x7FFFu + ((u >> 16) & 1u);
    return (unsigned short)(u >> 16);
}

// ---------------------------------------------------------------------------
// Pack fp32 W (K x N row-major) into hi/lo bf16 padded tile images:
// img(L,nt,kt)[n*40+k] = W[kt*32+k][nt*128+n]; W ~= hi + lo (bf16 pair)
// ---------------------------------------------------------------------------
__global__ void pack_w_hl(const float* __restrict__ w1,
                          const float* __restrict__ w2,
                          const float* __restrict__ w3,
                          unsigned short* __restrict__ wph,
                          unsigned short* __restrict__ wpl) {
    const int kt = blockIdx.x, nt = blockIdx.y, L = blockIdx.z;
    const float* W = (L == 0) ? w1 : ((L == 1) ? w2 : w3);
    __shared__ float tl[128 * 33];   // [n][k] transposed, padded
    const int tid = threadIdx.x;
    const int k  = tid >> 3;          // 0..31
    const int nc = (tid & 7) * 16;    // 0..112
    const float* src = W + (size_t)(kt * 32 + k) * HID + nt * 128 + nc;
    #pragma unroll
    for (int j = 0; j < 16; ++j) tl[(nc + j) * 33 + k] = src[j];
    __syncthreads();
    const size_t base = (size_t)(L * 1024 + nt * 64 + kt) * BIMG;
    for (int e = tid; e < BIMG; e += 256) {
        int n = e / 40, kk = e - n * 40;
        float a = (kk < 32) ? tl[n * 33 + kk] : 0.f;
        unsigned short hs = f2bf(a);
        wph[base + e] = hs;
        wpl[base + e] = f2bf(a - bf2f(hs));
    }
}

// ---------------------------------------------------------------------------
// Layer 0 (pair out): v=relu(xs*w0+b0); store bf16 hi/lo pair, row-major
// ---------------------------------------------------------------------------
__global__ void layer0p(const float* __restrict__ xs,
                        const float* __restrict__ w0,
                        const float* __restrict__ b0,
                        unsigned short* __restrict__ Ahg,
                        unsigned short* __restrict__ Alg, int row0) {
    const int r = blockIdx.x;
    const int grow = row0 + r;
    const int j = threadIdx.x * 8;
    const float x = (grow < MPTS) ? xs[grow] : 0.f;
    bf16x8 h, l;
    #pragma unroll
    for (int q = 0; q < 8; ++q) {
        float v = x * w0[j + q] + b0[j + q];
        v = v > 0.f ? v : 0.f;
        unsigned short hs = f2bf(v);
        h[q] = (short)hs;
        l[q] = (short)f2bf(v - bf2f(hs));
    }
    *(bf16x8*)(Ahg + (size_t)r * HID + j) = h;
    *(bf16x8*)(Alg + (size_t)r * HID + j) = l;
}

// ---------------------------------------------------------------------------
// MFMA GEMM, conversion-free staging: A carried as bf16 hi/lo pair (row-major),
// W pre-split images. C written as bf16 hi/lo pair. 128x128 tile, BK=32,
// 4 waves of 64x64, 3 MFMA per fragment pair (AhBh + AlBh + AhBl).
// ---------------------------------------------------------------------------
__launch_bounds__(256, 3)
__global__ void gemm_hl(const unsigned short* __restrict__ Ahg,
                        const unsigned short* __restrict__ Alg,
                        const unsigned short* __restrict__ wph,
                        const unsigned short* __restrict__ wpl,
                        const float* __restrict__ bias,
                        unsigned short* __restrict__ Chg,
                        unsigned short* __restrict__ Clg, int layer) {
    __shared__ short Ah[128 * 40];
    __shared__ short Al[128 * 40];
    __shared__ short Bh[128 * 40];
    __shared__ short Bl[128 * 40];

    const int tid  = threadIdx.x;
    const int lane = tid & 63;
    const int wave = tid >> 6;
    const int quad = lane >> 4;
    const int lidx = lane & 15;
    const int nt = blockIdx.x;
    const int m0 = blockIdx.y * 128;    // chunk-local
    const int mbase = (wave >> 1) * 64;
    const int nbase = (wave & 1) * 64;

    const size_t wbase = (size_t)(layer * 1024 + nt * 64) * BIMG;
    const bf16x8* gBH = (const bf16x8*)(wph + wbase);
    const bf16x8* gBL = (const bf16x8*)(wpl + wbase);

    // A staging: 512 chunks of 8 shorts (128 rows x 4 kchunks); 2 per thread
    const int mr0 = tid >> 2,         kc0 = tid & 3;
    const int mr1 = (tid + 256) >> 2, kc1 = (tid + 256) & 3;
    const unsigned short* a0h = Ahg + (size_t)(m0 + mr0) * HID + kc0 * 8;
    const unsigned short* a1h = Ahg + (size_t)(m0 + mr1) * HID + kc1 * 8;
    const unsigned short* a0l = Alg + (size_t)(m0 + mr0) * HID + kc0 * 8;
    const unsigned short* a1l = Alg + (size_t)(m0 + mr1) * HID + kc1 * 8;

    f32x4 acc[4][4];
    #pragma unroll
    for (int i = 0; i < 4; ++i)
        #pragma unroll
        for (int j = 0; j < 4; ++j) acc[i][j] = (f32x4)0.f;

    for (int kt = 0; kt < KTIL; ++kt) {
        // ---- global prefetch into VGPRs (pure moves, no conversion) ----
        const int ko = kt * 32;
        bf16x8 ah0 = *(const bf16x8*)(a0h + ko);
        bf16x8 ah1 = *(const bf16x8*)(a1h + ko);
        bf16x8 al0 = *(const bf16x8*)(a0l + ko);
        bf16x8 al1 = *(const bf16x8*)(a1l + ko);

        const int kb = kt * 640;   // vec8 chunks per k-step image
        bf16x8 bh0 = gBH[kb + tid];
        bf16x8 bh1 = gBH[kb + tid + 256];
        bf16x8 bl0 = gBL[kb + tid];
        bf16x8 bl1 = gBL[kb + tid + 256];
        bf16x8 bh2, bl2;
        if (tid < 128) { bh2 = gBH[kb + tid + 512]; bl2 = gBL[kb + tid + 512]; }

        __syncthreads();   // prior iteration's fragment reads done

        *(bf16x8*)(&Ah[mr0 * 40 + kc0 * 8]) = ah0;
        *(bf16x8*)(&Ah[mr1 * 40 + kc1 * 8]) = ah1;
        *(bf16x8*)(&Al[mr0 * 40 + kc0 * 8]) = al0;
        *(bf16x8*)(&Al[mr1 * 40 + kc1 * 8]) = al1;
        ((bf16x8*)Bh)[tid]       = bh0;  ((bf16x8*)Bl)[tid]       = bl0;
        ((bf16x8*)Bh)[tid + 256] = bh1;  ((bf16x8*)Bl)[tid + 256] = bl1;
        if (tid < 128) { ((bf16x8*)Bh)[tid + 512] = bh2; ((bf16x8*)Bl)[tid + 512] = bl2; }

        __syncthreads();   // staging visible

        bf16x8 afh[4], afl[4], bfh[4], bfl[4];
        #pragma unroll
        for (int mm = 0; mm < 4; ++mm) {
            int r = mbase + mm * 16 + lidx;
            afh[mm] = *(const bf16x8*)(&Ah[r * 40 + quad * 8]);
            afl[mm] = *(const bf16x8*)(&Al[r * 40 + quad * 8]);
        }
        #pragma unroll
        for (int nn = 0; nn < 4; ++nn) {
            int r = nbase + nn * 16 + lidx;
            bfh[nn] = *(const bf16x8*)(&Bh[r * 40 + quad * 8]);
            bfl[nn] = *(const bf16x8*)(&Bl[r * 40 + quad * 8]);
        }
        #pragma unroll
        for (int mm = 0; mm < 4; ++mm)
            #pragma unroll
            for (int nn = 0; nn < 4; ++nn) {
                acc[mm][nn] = __builtin_amdgcn_mfma_f32_16x16x32_bf16(afh[mm], bfh[nn], acc[mm][nn], 0, 0, 0);
                acc[mm][nn] = __builtin_amdgcn_mfma_f32_16x16x32_bf16(afl[mm], bfh[nn], acc[mm][nn], 0, 0, 0);
                acc[mm][nn] = __builtin_amdgcn_mfma_f32_16x16x32_bf16(afh[mm], bfl[nn], acc[mm][nn], 0, 0, 0);
            }
    }

    // epilogue: C/D layout col=lane&15, row=quad*4+reg; write hi/lo pair
    #pragma unroll
    for (int nn = 0; nn < 4; ++nn) {
        const int col = nt * 128 + nbase + nn * 16 + lidx;
        const float bv = bias[col];
        #pragma unroll
        for (int mm = 0; mm < 4; ++mm) {
            const int mrow = m0 + mbase + mm * 16 + quad * 4;
            #pragma unroll
            for (int r = 0; r < 4; ++r) {
                float v = acc[mm][nn][r] + bv;
                v = v > 0.f ? v : 0.f;
                unsigned short hs = f2bf(v);
                Chg[(size_t)(mrow + r) * HID + col] = hs;
                Clg[(size_t)(mrow + r) * HID + col] = f2bf(v - bf2f(hs));
            }
        }
    }
}

// ---------------------------------------------------------------------------
// Layer 4 (pair in): Amg = relu(dot(Ah+Al, w4) + b4); one wave per row
// ---------------------------------------------------------------------------
__global__ void layer4p(const unsigned short* __restrict__ Ahg,
                        const unsigned short* __restrict__ Alg,
                        const float* __restrict__ w4,
                        const float* __restrict__ b4,
                        float* __restrict__ Amg, int row0) {
    const int lane = threadIdx.x & 63;
    const int wave = threadIdx.x >> 6;
    const int r    = blockIdx.x * 4 + wave;
    if (row0 + r >= MPTS) return;
    const unsigned short* ah = Ahg + (size_t)r * HID;
    const unsigned short* al = Alg + (size_t)r * HID;
    float s = 0.f;
    #pragma unroll
    for (int c = 0; c < 8; ++c) {
        const int col = c * 256 + lane * 4;
        bf16x4 hv = *(const bf16x4*)(ah + col);
        bf16x4 lv = *(const bf16x4*)(al + col);
        f32x4 wv = *(const f32x4*)(w4 + col);
        #pragma unroll
        for (int q = 0; q < 4; ++q)
            s += (bf2f((unsigned short)hv[q]) + bf2f((unsigned short)lv[q])) * wv[q];
    }
    #pragma unroll
    for (int off = 32; off; off >>= 1) s += __shfl_down(s, off);
    if (lane == 0) {
        float v = s + b4[0];
        Amg[row0 + r] = v > 0.f ? v : 0.f;
    }
}

// ---------------------------------------------------------------------------
// Fallback fp32 path (ws too small for packed images)
// ---------------------------------------------------------------------------
__global__ void layer0f(const float* __restrict__ xs, const float* __restrict__ w0,
                        const float* __restrict__ b0, float* __restrict__ A, int row0) {
    const int r = blockIdx.x;
    const int j = threadIdx.x * 8;
    const float x = (row0 + r < MPTS) ? xs[row0 + r] : 0.f;
    float* out = A + (size_t)r * HID + j;
    #pragma unroll
    for (int q = 0; q < 8; ++q) {
        float v = x * w0[j + q] + b0[j + q];
        out[q] = v > 0.f ? v : 0.f;
    }
}

__launch_bounds__(256)
__global__ void gemm_valu(const float* __restrict__ A, const float* __restrict__ W,
                          const float* __restrict__ bias, float* __restrict__ C) {
    __shared__ float As[16][132];
    __shared__ float Ws[16][132];
    const int tid = threadIdx.x;
    const int tx = tid & 15, ty = tid >> 4;
    const int n0 = blockIdx.x * 128;
    const int m0 = blockIdx.y * 128;
    const int am = tid & 127, ak = (tid >> 7) * 8;
    const int wn = (tid & 15) * 8, wk = tid >> 4;
    const float* aptr = A + (size_t)(m0 + am) * HID + ak;
    const float* wptr = W + (size_t)wk * HID + n0 + wn;
    float acc[8][8];
    #pragma unroll
    for (int i = 0; i < 8; ++i)
        #pragma unroll
        for (int j = 0; j < 8; ++j) acc[i][j] = 0.f;
    for (int k0 = 0; k0 < HID; k0 += 16) {
        f32x4 a0 = *(const f32x4*)(aptr + k0);
        f32x4 a1 = *(const f32x4*)(aptr + k0 + 4);
        f32x4 w0v = *(const f32x4*)(wptr + (size_t)k0 * HID);
        f32x4 w1v = *(const f32x4*)(wptr + (size_t)k0 * HID + 4);
        __syncthreads();
        As[ak + 0][am] = a0[0]; As[ak + 1][am] = a0[1];
        As[ak + 2][am] = a0[2]; As[ak + 3][am] = a0[3];
        As[ak + 4][am] = a1[0]; As[ak + 5][am] = a1[1];
        As[ak + 6][am] = a1[2]; As[ak + 7][am] = a1[3];
        *(f32x4*)&Ws[wk][wn]     = w0v;
        *(f32x4*)&Ws[wk][wn + 4] = w1v;
        __syncthreads();
        #pragma unroll
        for (int kk = 0; kk < 16; ++kk) {
            f32x4 av0 = *(const f32x4*)&As[kk][ty * 8];
            f32x4 av1 = *(const f32x4*)&As[kk][ty * 8 + 4];
            f32x4 bv0 = *(const f32x4*)&Ws[kk][tx * 8];
            f32x4 bv1 = *(const f32x4*)&Ws[kk][tx * 8 + 4];
            float a[8] = {av0[0], av0[1], av0[2], av0[3], av1[0], av1[1], av1[2], av1[3]};
            float b[8] = {bv0[0], bv0[1], bv0[2], bv0[3], bv1[0], bv1[1], bv1[2], bv1[3]};
            #pragma unroll
            for (int i = 0; i < 8; ++i)
                #pragma unroll
                for (int j = 0; j < 8; ++j) acc[i][j] += a[i] * b[j];
        }
    }
    #pragma unroll
    for (int i = 0; i < 8; ++i) {
        const int m = m0 + ty * 8 + i;
        #pragma unroll
        for (int jc = 0; jc < 2; ++jc) {
            const int n = n0 + tx * 8 + jc * 4;
            f32x4 v4;
            #pragma unroll
            for (int q = 0; q < 4; ++q) {
                float v = acc[i][jc * 4 + q] + bias[n + q];
                v4[q] = v > 0.f ? v : 0.f;
            }
            *(f32x4*)(C + (size_t)m * HID + n) = v4;
        }
    }
}

__global__ void layer4f(const float* __restrict__ A, const float* __restrict__ w4,
                        const float* __restrict__ b4, float* __restrict__ Amg, int row0) {
    const int lane = threadIdx.x & 63;
    const int wave = threadIdx.x >> 6;
    const int r    = blockIdx.x * 4 + wave;
    if (row0 + r >= MPTS) return;
    const float* ap = A + (size_t)r * HID;
    float s = 0.f;
    #pragma unroll
    for (int c = 0; c < 8; ++c) {
        const int col = c * 256 + lane * 4;
        f32x4 av = *(const f32x4*)(ap + col);
        f32x4 wv = *(const f32x4*)(w4 + col);
        s += av[0] * wv[0] + av[1] * wv[1] + av[2] * wv[2] + av[3] * wv[3];
    }
    #pragma unroll
    for (int off = 32; off; off >>= 1) s += __shfl_down(s, off);
    if (lane == 0) {
        float v = s + b4[0];
        Amg[row0 + r] = v > 0.f ? v : 0.f;
    }
}

// ---------------------------------------------------------------------------
// Multigrid level: interp (2n-1) + band overwrite; all fp32 (d_out is fp32).
// ---------------------------------------------------------------------------
__global__ void mg_level(const float* __restrict__ in, float* __restrict__ outf,
                         const int* __restrict__ nbrs_base, int level,
                         const float* __restrict__ band, int n_out) {
    const int j = blockIdx.x * 256 + threadIdx.x;
    if (j >= n_out) return;
    float v;
    if (j & 1) v = 0.5f * (in[j >> 1] + in[(j >> 1) + 1]);
    else       v = in[j >> 1];
    const int stride =
        (nbrs_base[1] == 0 && nbrs_base[3] == 0 && nbrs_base[5] == 0) ? 2 : 1;
    #pragma unroll
    for (int t = 0; t < 8; ++t) {
        const int idx = nbrs_base[(level * 8 + t) * stride];
        if (j == idx) v = band[t];
    }
    outf[j] = v;
}

// ---------------------------------------------------------------------------
extern "C" void kernel_launch(void* const* d_in, const int* in_sizes, int n_in,
                              void* d_out, int out_size, void* d_ws, size_t ws_size,
                              hipStream_t stream) {
    // ---- input order detection: dict (documented) / signature / alphabetical
    int iXS=0, iNB=1, iW0=4, iB0=5, iW1=6, iB1=7, iW2=8, iB2=9,
        iW3=10, iB3=11, iW4=12, iB4=13;                       // dict default
    if (n_in >= 14) {
        if (in_sizes[0] == HID) {
            iB0=0; iB1=1; iB2=2; iB3=3; iB4=4; iNB=7;
            iW0=8; iW1=9; iW2=10; iW3=11; iW4=12; iXS=13;
        } else if (!(in_sizes[1] == 40 || in_sizes[1] == 80)) {
            iXS=0; iW0=1; iB0=2; iW1=3; iB1=4; iW2=5; iB2=6;
            iW3=7; iB3=8; iW4=9; iB4=10; iNB=11;
        }
    }
    const float* xs = (const float*)d_in[iXS];
    const int* nbrs = (const int*)d_in[iNB];
    const float* w0 = (const float*)d_in[iW0];
    const float* b0 = (const float*)d_in[iB0];
    const float* w1 = (const float*)d_in[iW1];
    const float* b1 = (const float*)d_in[iB1];
    const float* w2 = (const float*)d_in[iW2];
    const float* b2 = (const float*)d_in[iB2];
    const float* w3 = (const float*)d_in[iW3];
    const float* b3 = (const float*)d_in[iB3];
    const float* w4 = (const float*)d_in[iW4];
    const float* b4 = (const float*)d_in[iB4];

    // ---- workspace layout ----
    char* ws = (char*)d_ws;
    const size_t szAmg = 66048;
    const size_t szAh1 = 524544;
    const size_t szAh2 = 1048832;
    float* Amg = (float*)(ws);
    float* ahA = (float*)(ws + szAmg);
    float* ahB = (float*)(ws + szAmg + szAh1);
    const size_t casc_end = szAmg + szAh1 + szAh2;       // 1,639,424
    const size_t szWHL  = 2ull * 3 * 1024 * BIMG * 2;    // 62,914,560 (hi+lo)
    const size_t per_tile = 2ull * 128 * HID * 4;        // 2 MB (4 bf16 act bufs)

    const int use_mfma = (ws_size >= casc_end + szWHL + per_tile) ? 1 : 0;

    unsigned short* wph = (unsigned short*)(ws + casc_end);
    unsigned short* wpl = wph + (size_t)3 * 1024 * BIMG;
    const size_t buf_start = use_mfma ? (casc_end + szWHL) : casc_end;

    size_t avail = ws_size - buf_start;
    int CT = (int)(avail / per_tile);
    if (CT < 1) CT = 1;
    if (CT > MTILES) CT = MTILES;

    if (use_mfma) {
        const size_t half = (size_t)CT * 128 * HID * 2;   // one bf16 act buffer
        unsigned short* bAh = (unsigned short*)(ws + buf_start);
        unsigned short* bAl = bAh + half / 2;
        unsigned short* bBh = bAh + 2 * (half / 2);
        unsigned short* bBl = bAh + 3 * (half / 2);

        pack_w_hl<<<dim3(KTIL, NTIL, 3), 256, 0, stream>>>(w1, w2, w3, wph, wpl);

        for (int t0 = 0; t0 < MTILES; t0 += CT) {
            int tiles = (MTILES - t0 < CT) ? (MTILES - t0) : CT;
            int row0 = t0 * 128;
            layer0p<<<dim3(tiles * 128), 256, 0, stream>>>(xs, w0, b0, bAh, bAl, row0);
            dim3 ggrid(NTIL, tiles);
            gemm_hl<<<ggrid, 256, 0, stream>>>(bAh, bAl, wph, wpl, b1, bBh, bBl, 0);
            gemm_hl<<<ggrid, 256, 0, stream>>>(bBh, bBl, wph, wpl, b2, bAh, bAl, 1);
            gemm_hl<<<ggrid, 256, 0, stream>>>(bAh, bAl, wph, wpl, b3, bBh, bBl, 2);
            layer4p<<<dim3(tiles * 32), 256, 0, stream>>>(bBh, bBl, w4, b4, Amg, row0);
        }
    } else {
        float* bufA = (float*)(ws + buf_start);
        float* bufB = (float*)(ws + buf_start + (size_t)CT * 128 * HID * 4);
        for (int t0 = 0; t0 < MTILES; t0 += CT) {
            int tiles = (MTILES - t0 < CT) ? (MTILES - t0) : CT;
            int row0 = t0 * 128;
            layer0f<<<dim3(tiles * 128), 256, 0, stream>>>(xs, w0, b0, bufA, row0);
            dim3 ggrid(NTIL, tiles);
            gemm_valu<<<ggrid, 256, 0, stream>>>(bufA, w1, b1, bufB);
            gemm_valu<<<ggrid, 256, 0, stream>>>(bufB, w2, b2, bufA);
            gemm_valu<<<ggrid, 256, 0, stream>>>(bufA, w3, b3, bufB);
            layer4f<<<dim3(tiles * 32), 256, 0, stream>>>(bufB, w4, b4, Amg, row0);
        }
    }

    // multigrid cascade: 16385 -> ... -> 524289; level 4 writes d_out (fp32)
    const float* cur = Amg + 40;
    float* dsts[5] = {ahA, ahB, ahA, ahB, (float*)d_out};
    int n = 16385;
    for (int i = 0; i < 5; ++i) {
        int n_out = 2 * n - 1;
        mg_level<<<dim3((n_out + 255) / 256), 256, 0, stream>>>(
            cur, dsts[i], nbrs, i, Amg + 8 * (4 - i), n_out);
        cur = dsts[i];
        n = n_out;
    }
    (void)out_size;
}